// Round 12
// baseline (62.388 us; speedup 1.0000x reference)
//
#include <hip/hip_runtime.h>
#include <math.h>

#define Bdim 8
#define Cdim 64
#define Ndim 4096
#define TK   32            // keys per tile
#define GNT  32            // tiles per key-group (1024 keys / 32)

typedef __bf16 bf16x8 __attribute__((ext_vector_type(8)));
typedef __bf16 bf16x4 __attribute__((ext_vector_type(4)));
typedef float  f32x4  __attribute__((ext_vector_type(4)));
typedef float  f32x16 __attribute__((ext_vector_type(16)));

__device__ __forceinline__ void gload_lds16(const void* g, void* l) {
    __builtin_amdgcn_global_load_lds(
        (const __attribute__((address_space(1))) void*)g,
        (__attribute__((address_space(3))) void*)l, 16, 0, 0);
}

__device__ __forceinline__ float fexp2(float x) {
#if __has_builtin(__builtin_amdgcn_exp2f)
    return __builtin_amdgcn_exp2f(x);
#else
    return exp2f(x);
#endif
}

// ---------------------------------------------------------------------------
// Kernel 1: QKV projection via MFMA, hi/lo split (~fp32), fused W-conversion
// (r11, validated). Adds: fgbias precompute (f32: 0 -> -12, masked -> -1e30)
// written by jc==1 blocks. Q pre-scaled by (1/sqrt(C))*log2(e).
//   Qb [B][N][C], Kb [B][N][C], Vb [B][C][N]   (bf16)
// ---------------------------------------------------------------------------
__global__ __launch_bounds__(256) void qkv_mfma_kernel(
    const float* __restrict__ x, const float* __restrict__ w_qkv,
    const int* __restrict__ fg,
    __bf16* __restrict__ Qb, __bf16* __restrict__ Kb, __bf16* __restrict__ Vb,
    float* __restrict__ fgb)
{
    __shared__ __align__(16) __bf16 whs[64 * 64];
    __shared__ __align__(16) __bf16 wls[64 * 64];
    __shared__ __align__(16) __bf16 tr[4][16 * 64];

    const int bx   = blockIdx.x;
    const int jc   = bx % 3;                 // 0=Q, 1=K, 2=V
    const int nblk = (bx / 3) & 63;
    const int b    = bx / 192;
    const int tid  = threadIdx.x;
    const int wv   = tid >> 6;
    const int l    = tid & 63;
    const int g    = l >> 4;
    const int li   = l & 15;
    const int nbase = nblk * 64 + wv * 16;

    const float KS = 0.125f * 1.44269504089f;

    if (jc == 1 && tid < 64) {
        const int n = nblk * 64 + tid;
        fgb[b * Ndim + n] = fg[b * Ndim + n] ? -12.f : -1e30f;
    }

    // ---- convert this block's W slice into LDS hi/lo (swizzled) ----
    {
        const float* wsrc = w_qkv + jc * 4096 + tid * 16;
        const float4 f0 = *(const float4*)(wsrc);
        const float4 f1 = *(const float4*)(wsrc + 4);
        const float4 f2 = *(const float4*)(wsrc + 8);
        const float4 f3 = *(const float4*)(wsrc + 12);
        const int row = tid >> 2;
        const int gb  = (tid & 3) * 2;
        bf16x8 h0, l0, h1, l1;
        const float* fp[4] = {(const float*)&f0, (const float*)&f1,
                              (const float*)&f2, (const float*)&f3};
#pragma unroll
        for (int qq = 0; qq < 2; ++qq)
#pragma unroll
            for (int e = 0; e < 8; ++e) {
                const float v = fp[qq * 2 + (e >> 2)][e & 3];
                const __bf16 h = (__bf16)v;
                if (qq == 0) { h0[e] = h; l0[e] = (__bf16)(v - (float)h); }
                else         { h1[e] = h; l1[e] = (__bf16)(v - (float)h); }
            }
        *(bf16x8*)(whs + row * 64 + 8 * ((gb)     ^ (row & 7))) = h0;
        *(bf16x8*)(whs + row * 64 + 8 * ((gb + 1) ^ (row & 7))) = h1;
        *(bf16x8*)(wls + row * 64 + 8 * ((gb)     ^ (row & 7))) = l0;
        *(bf16x8*)(wls + row * 64 + 8 * ((gb + 1) ^ (row & 7))) = l1;
    }

    bf16x8 xhi[2], xlo[2];
#pragma unroll
    for (int kc = 0; kc < 2; ++kc)
#pragma unroll
        for (int jj = 0; jj < 8; ++jj) {
            const int c = kc * 32 + 8 * g + jj;
            const float v = x[((size_t)(b * 64 + c)) * Ndim + nbase + li];
            const __bf16 h = (__bf16)v;
            xhi[kc][jj] = h;
            xlo[kc][jj] = (__bf16)(v - (float)h);
        }
    __syncthreads();

    __bf16* trw = tr[wv];
    const float qs = (jc == 0) ? KS : 1.f;

#pragma unroll
    for (int jt = 0; jt < 4; ++jt) {
        const int rw = 16 * jt + li;
        const int rs = li & 7;
        const bf16x8 ah0 = *(const bf16x8*)(whs + rw * 64 + 8 * (g ^ rs));
        const bf16x8 ah1 = *(const bf16x8*)(whs + rw * 64 + 8 * ((4 + g) ^ rs));
        const bf16x8 al0 = *(const bf16x8*)(wls + rw * 64 + 8 * (g ^ rs));
        const bf16x8 al1 = *(const bf16x8*)(wls + rw * 64 + 8 * ((4 + g) ^ rs));
        f32x4 d = (f32x4){0.f, 0.f, 0.f, 0.f};
        d = __builtin_amdgcn_mfma_f32_16x16x32_bf16(ah0, xhi[0], d, 0, 0, 0);
        d = __builtin_amdgcn_mfma_f32_16x16x32_bf16(ah1, xhi[1], d, 0, 0, 0);
        d = __builtin_amdgcn_mfma_f32_16x16x32_bf16(ah0, xlo[0], d, 0, 0, 0);
        d = __builtin_amdgcn_mfma_f32_16x16x32_bf16(ah1, xlo[1], d, 0, 0, 0);
        d = __builtin_amdgcn_mfma_f32_16x16x32_bf16(al0, xhi[0], d, 0, 0, 0);
        d = __builtin_amdgcn_mfma_f32_16x16x32_bf16(al1, xhi[1], d, 0, 0, 0);

        if (jc == 2) {
#pragma unroll
            for (int r = 0; r < 4; ++r) {
                const int cv = jt * 16 + 4 * g + r;
                Vb[((size_t)(b * 64 + cv)) * Ndim + nbase + li] = (__bf16)d[r];
            }
        } else {
            bf16x4 pk;
#pragma unroll
            for (int r = 0; r < 4; ++r) pk[r] = (__bf16)(d[r] * qs);
            const int gran = (2 * jt + (g >> 1)) ^ (li & 7);
            *(bf16x4*)(trw + li * 64 + gran * 8 + 4 * (g & 1)) = pk;
        }
    }

    if (jc != 2) {
        __bf16* dstm = ((jc == 0) ? Qb : Kb) + ((size_t)b * Ndim + nbase) * 64;
#pragma unroll
        for (int p = 0; p < 2; ++p) {
            const int row = p * 8 + (l >> 3);
            const uint4 vr = *(const uint4*)(
                trw + row * 64 + ((l & 7) ^ (l >> 3)) * 8);
            *(uint4*)(dstm + row * 64 + 8 * (l & 7)) = vr;
        }
    }
}

// ---------------------------------------------------------------------------
// Kernel 2: MFMA flash attention, 32x32x16 shape, fixed-shift softmax.
// 8 waves = 4 key-groups x 2 q-subtiles of 32 q (q = lane&31, hi = lane>>5).
// K rows staged with pi = swap(bit2,bit3): lane's 16 scores ARE the two PV
// B-frags in natural key order. V^T natural order. Out-proj feeds B-frags
// from merged O regs with the same sigma-permutation applied to W columns.
// Mask bias f32 from precomputed fgb via gload_lds. Batch->XCD swizzle.
// ---------------------------------------------------------------------------
__global__ __launch_bounds__(512, 4) void attn_kernel(
    const __bf16* __restrict__ Qb, const __bf16* __restrict__ Kb,
    const __bf16* __restrict__ Vb, const float* __restrict__ fgb,
    const float* __restrict__ w_proj, const float* __restrict__ b_proj,
    float* __restrict__ out)
{
    __shared__ __align__(16) __bf16 kt[4][2][TK * 64];   // [grp][buf][R][c]  32 KB
    __shared__ __align__(16) __bf16 vt[4][2][64 * TK];   // [grp][buf][c][k]  32 KB
    __shared__ __align__(16) float  mtf[4][2][TK];       // mask bias (f32)   1 KB

    const int bx   = blockIdx.x;
    const int b    = bx & 7;
    const int qblk = (bx >> 3) & 63;
    const int tid  = threadIdx.x;
    const int wv   = tid >> 6;
    const int grp  = wv >> 1;
    const int wsub = wv & 1;
    const int l    = tid & 63;
    const int q    = l & 31;
    const int hi   = l >> 5;

    // Q B-frags: B[k=8hi+j+16s][col=q]
    const int qrow = qblk * 64 + wsub * 32 + q;
    const __bf16* qbp = Qb + ((size_t)b * Ndim + qrow) * 64;
    bf16x8 qf[4];
#pragma unroll
    for (int s = 0; s < 4; ++s)
        qf[s] = *(const bf16x8*)(qbp + 16 * s + 8 * hi);

    // ---- staging geometry ----
    const int kbase0 = grp * 1024;
    const __bf16* ksrcc[2];
    const __bf16* vsrcc[2];
    int kdst[2], vdst[2];
#pragma unroll
    for (int cc = 0; cc < 2; ++cc) {
        const int R  = wsub * 16 + cc * 8 + (l >> 3);
        const int pi = (R & 19) | ((R & 4) << 1) | ((R & 8) >> 1);  // swap b2<->b3
        ksrcc[cc] = Kb + ((size_t)b * Ndim + kbase0 + pi) * 64 + 8 * ((l & 7) ^ (R & 7));
        kdst[cc]  = (wsub * 16 + cc * 8) * 64;
        const int row = wsub * 32 + cc * 16 + (l >> 2);
        vsrcc[cc] = Vb + ((size_t)(b * 64 + row)) * Ndim + kbase0
                  + 8 * ((l & 3) ^ ((row >> 1) & 3));
        vdst[cc]  = (wsub * 32 + cc * 16) * TK;
    }
    const float* fgbp = fgb + b * Ndim + kbase0;

    auto stage = [&](int t, int buf) {
#pragma unroll
        for (int cc = 0; cc < 2; ++cc)
            gload_lds16(ksrcc[cc] + (size_t)t * (TK * 64), &kt[grp][buf][kdst[cc]]);
#pragma unroll
        for (int cc = 0; cc < 2; ++cc)
            gload_lds16(vsrcc[cc] + t * TK, &vt[grp][buf][vdst[cc]]);
        if (wsub == 0 && l < 8)
            gload_lds16(fgbp + t * 32 + l * 4, &mtf[grp][buf][0]);
    };

    f32x16 acc0 = {}, acc1 = {};
    f32x4  psv  = {};

    stage(0, 0);

    for (int it = 0; it < GNT; ++it) {
        const int buf = it & 1;
        __syncthreads();                  // tile resident
        if (it + 1 < GNT) stage(it + 1, buf ^ 1);

        // mask bias -> C-init: z[r] = bias[key (r&7)+8hi+16(r>>3)]
        const float* mrow = &mtf[grp][buf][0];
        const f32x4 ma = *(const f32x4*)(mrow + 8 * hi);
        const f32x4 mb = *(const f32x4*)(mrow + 8 * hi + 4);
        const f32x4 mc = *(const f32x4*)(mrow + 16 + 8 * hi);
        const f32x4 md = *(const f32x4*)(mrow + 20 + 8 * hi);
        f32x16 z;
#pragma unroll
        for (int r = 0; r < 4; ++r) {
            z[r] = ma[r]; z[4 + r] = mb[r]; z[8 + r] = mc[r]; z[12 + r] = md[r];
        }

        // ---- S^T = K Q^T (one 32x32 tile, K-dim 64 = 4 MFMA) ----
        __builtin_amdgcn_s_setprio(1);
#pragma unroll
        for (int s = 0; s < 4; ++s) {
            const bf16x8 kf = *(const bf16x8*)(
                &kt[grp][buf][q * 64 + 8 * ((hi + 2 * s) ^ (q & 7))]);
            z = __builtin_amdgcn_mfma_f32_32x32x16_bf16(kf, qf[s], z, 0, 0, 0);
        }
        __builtin_amdgcn_s_setprio(0);

        // ---- p = exp2(s); per-lane partial row-sums ----
        f32x16 p;
#pragma unroll
        for (int r = 0; r < 16; ++r) {
            p[r] = fexp2(z[r]);
            psv[r & 3] += p[r];
        }
        bf16x8 pb0, pb1;
#pragma unroll
        for (int j = 0; j < 8; ++j) {
            pb0[j] = (__bf16)p[j];
            pb1[j] = (__bf16)p[8 + j];
        }

        // ---- O^T += V^T P^T (2 c-halves x 2 K-pieces) ----
        __builtin_amdgcn_s_setprio(1);
#pragma unroll
        for (int h = 0; h < 2; ++h) {
            const int c   = 32 * h + q;
            const int csw = (c >> 1) & 3;
            const bf16x8 vf0 = *(const bf16x8*)(&vt[grp][buf][c * 32 + 8 * ((hi)     ^ csw)]);
            const bf16x8 vf1 = *(const bf16x8*)(&vt[grp][buf][c * 32 + 8 * ((hi + 2) ^ csw)]);
            if (h == 0) {
                acc0 = __builtin_amdgcn_mfma_f32_32x32x16_bf16(vf0, pb0, acc0, 0, 0, 0);
                acc0 = __builtin_amdgcn_mfma_f32_32x32x16_bf16(vf1, pb1, acc0, 0, 0, 0);
            } else {
                acc1 = __builtin_amdgcn_mfma_f32_32x32x16_bf16(vf0, pb0, acc1, 0, 0, 0);
                acc1 = __builtin_amdgcn_mfma_f32_32x32x16_bf16(vf1, pb1, acc1, 0, 0, 0);
            }
        }
        __builtin_amdgcn_s_setprio(0);
    }

    // ---- row-sum: horizontal + cross-hi (once) ----
    float lsum = (psv[0] + psv[1]) + (psv[2] + psv[3]);
    lsum += __shfl_xor(lsum, 32);

    // ---- 4-way merge via LDS overlay (plain sums, shared fixed shift) ----
    float* mlb = (float*)&kt[0][0][0];
    __syncthreads();

    auto chunk = [&](int cidx) -> float* {
        return (cidx < 4) ? (float*)&vt[0][0][0] + cidx * 2048
                          : mlb + 256 + (cidx - 4) * 2048;
    };

    if (grp > 0) {
        const int pp = grp - 1;
        if (l < 32) mlb[(pp * 2 + wsub) * 32 + l] = lsum;
        float* o = chunk(pp * 2 + wsub);
#pragma unroll
        for (int fi = 0; fi < 8; ++fi) {
            f32x4 v;
#pragma unroll
            for (int e = 0; e < 4; ++e)
                v[e] = (fi < 4) ? acc0[(fi & 3) * 4 + e] : acc1[(fi & 3) * 4 + e];
            *(f32x4*)(o + (fi * 64 + l) * 4) = v;
        }
    }
    __syncthreads();
    if (grp > 0) return;

    float Lt = lsum;
#pragma unroll
    for (int pp = 0; pp < 3; ++pp)
        Lt += mlb[(pp * 2 + wsub) * 32 + q];
    const float inv = 1.f / Lt;

    f32x16 m0 = acc0, m1 = acc1;
#pragma unroll
    for (int pp = 0; pp < 3; ++pp) {
        const float* o = chunk(pp * 2 + wsub);
#pragma unroll
        for (int fi = 0; fi < 8; ++fi) {
            const f32x4 v = *(const f32x4*)(o + (fi * 64 + l) * 4);
#pragma unroll
            for (int e = 0; e < 4; ++e) {
                if (fi < 4) m0[(fi & 3) * 4 + e] += v[e];
                else        m1[(fi & 3) * 4 + e] += v[e];
            }
        }
    }

    // ---- normalized O -> B-frags (sigma-permuted k order, lane-local) ----
    bf16x8 ob[4];
#pragma unroll
    for (int s = 0; s < 4; ++s)
#pragma unroll
        for (int j = 0; j < 8; ++j) {
            const float vv = (s < 2) ? m0[j + 8 * (s & 1)] : m1[j + 8 * (s & 1)];
            ob[s][j] = (__bf16)(vv * inv);
        }

    // ---- fused out-projection: W columns sigma-permuted to match ----
    const int nb = qblk * 64 + wsub * 32;
#pragma unroll
    for (int H = 0; H < 2; ++H) {
        const int co = 32 * H + q;
        f32x16 y = {};
#pragma unroll
        for (int s = 0; s < 4; ++s) {
            const float* wr = w_proj + co * 64 + 4 * hi + 16 * s;
            const float4 fA = *(const float4*)(wr);
            const float4 fB = *(const float4*)(wr + 8);
            bf16x8 wf;
            wf[0] = (__bf16)fA.x; wf[1] = (__bf16)fA.y;
            wf[2] = (__bf16)fA.z; wf[3] = (__bf16)fA.w;
            wf[4] = (__bf16)fB.x; wf[5] = (__bf16)fB.y;
            wf[6] = (__bf16)fB.z; wf[7] = (__bf16)fB.w;
            y = __builtin_amdgcn_mfma_f32_32x32x16_bf16(wf, ob[s], y, 0, 0, 0);
        }
#pragma unroll
        for (int rq = 0; rq < 4; ++rq) {
            const f32x4 bp = *(const f32x4*)(b_proj + 32 * H + 4 * hi + 8 * rq);
#pragma unroll
            for (int e = 0; e < 4; ++e) {
                const int co2 = 32 * H + e + 8 * rq + 4 * hi;
                out[((size_t)(b * 64 + co2)) * Ndim + nb + q] = y[rq * 4 + e] + bp[e];
            }
        }
    }
}

extern "C" void kernel_launch(void* const* d_in, const int* in_sizes, int n_in,
                              void* d_out, int out_size, void* d_ws, size_t ws_size,
                              hipStream_t stream) {
    const float* x      = (const float*)d_in[0];
    const int*   fg     = (const int*)d_in[1];
    const float* w_qkv  = (const float*)d_in[2];
    const float* w_proj = (const float*)d_in[3];
    const float* b_proj = (const float*)d_in[4];
    float* out = (float*)d_out;

    const size_t per = (size_t)Bdim * Cdim * Ndim;   // 2,097,152 elems
    __bf16* Qb  = (__bf16*)d_ws;
    __bf16* Kb  = Qb + per;
    __bf16* Vb  = Kb + per;
    float*  fgb = (float*)(Vb + per);                // 128 KB

    qkv_mfma_kernel<<<dim3(Bdim * (Ndim / 64) * 3), dim3(256), 0, stream>>>(
        x, w_qkv, fg, Qb, Kb, Vb, fgb);
    attn_kernel<<<dim3(Bdim * (Ndim / 64)), dim3(512), 0, stream>>>(
        Qb, Kb, Vb, fgb, w_proj, b_proj, out);
}

// Round 13
// 61.963 us; speedup vs baseline: 1.0069x; 1.0069x over previous
//
#include <hip/hip_runtime.h>
#include <math.h>

#define Bdim 8
#define Cdim 64
#define Ndim 4096
#define TK   32            // keys per tile
#define GNT  32            // tiles per key-group (1024 keys / 32)

typedef __bf16 bf16x8 __attribute__((ext_vector_type(8)));
typedef __bf16 bf16x4 __attribute__((ext_vector_type(4)));
typedef float  f32x4  __attribute__((ext_vector_type(4)));
typedef float  f32x16 __attribute__((ext_vector_type(16)));

__device__ __forceinline__ void gload_lds16(const void* g, void* l) {
    __builtin_amdgcn_global_load_lds(
        (const __attribute__((address_space(1))) void*)g,
        (__attribute__((address_space(3))) void*)l, 16, 0, 0);
}

__device__ __forceinline__ float fexp2(float x) {
#if __has_builtin(__builtin_amdgcn_exp2f)
    return __builtin_amdgcn_exp2f(x);
#else
    return exp2f(x);
#endif
}

// ---------------------------------------------------------------------------
// Kernel 1: QKV projection via MFMA, hi/lo split (~fp32), fused W-conversion
// (r11, validated). fgbias precompute (f32: 0 -> -12, masked -> -1e30).
// Q pre-scaled by (1/sqrt(C))*log2(e).
//   Qb [B][N][C], Kb [B][N][C], Vb [B][C][N]   (bf16)
// ---------------------------------------------------------------------------
__global__ __launch_bounds__(256) void qkv_mfma_kernel(
    const float* __restrict__ x, const float* __restrict__ w_qkv,
    const int* __restrict__ fg,
    __bf16* __restrict__ Qb, __bf16* __restrict__ Kb, __bf16* __restrict__ Vb,
    float* __restrict__ fgb)
{
    __shared__ __align__(16) __bf16 whs[64 * 64];
    __shared__ __align__(16) __bf16 wls[64 * 64];
    __shared__ __align__(16) __bf16 tr[4][16 * 64];

    const int bx   = blockIdx.x;
    const int jc   = bx % 3;                 // 0=Q, 1=K, 2=V
    const int nblk = (bx / 3) & 63;
    const int b    = bx / 192;
    const int tid  = threadIdx.x;
    const int wv   = tid >> 6;
    const int l    = tid & 63;
    const int g    = l >> 4;
    const int li   = l & 15;
    const int nbase = nblk * 64 + wv * 16;

    const float KS = 0.125f * 1.44269504089f;

    if (jc == 1 && tid < 64) {
        const int n = nblk * 64 + tid;
        fgb[b * Ndim + n] = fg[b * Ndim + n] ? -12.f : -1e30f;
    }

    // ---- convert this block's W slice into LDS hi/lo (swizzled) ----
    {
        const float* wsrc = w_qkv + jc * 4096 + tid * 16;
        const float4 f0 = *(const float4*)(wsrc);
        const float4 f1 = *(const float4*)(wsrc + 4);
        const float4 f2 = *(const float4*)(wsrc + 8);
        const float4 f3 = *(const float4*)(wsrc + 12);
        const int row = tid >> 2;
        const int gb  = (tid & 3) * 2;
        bf16x8 h0, l0, h1, l1;
        const float* fp[4] = {(const float*)&f0, (const float*)&f1,
                              (const float*)&f2, (const float*)&f3};
#pragma unroll
        for (int qq = 0; qq < 2; ++qq)
#pragma unroll
            for (int e = 0; e < 8; ++e) {
                const float v = fp[qq * 2 + (e >> 2)][e & 3];
                const __bf16 h = (__bf16)v;
                if (qq == 0) { h0[e] = h; l0[e] = (__bf16)(v - (float)h); }
                else         { h1[e] = h; l1[e] = (__bf16)(v - (float)h); }
            }
        *(bf16x8*)(whs + row * 64 + 8 * ((gb)     ^ (row & 7))) = h0;
        *(bf16x8*)(whs + row * 64 + 8 * ((gb + 1) ^ (row & 7))) = h1;
        *(bf16x8*)(wls + row * 64 + 8 * ((gb)     ^ (row & 7))) = l0;
        *(bf16x8*)(wls + row * 64 + 8 * ((gb + 1) ^ (row & 7))) = l1;
    }

    bf16x8 xhi[2], xlo[2];
#pragma unroll
    for (int kc = 0; kc < 2; ++kc)
#pragma unroll
        for (int jj = 0; jj < 8; ++jj) {
            const int c = kc * 32 + 8 * g + jj;
            const float v = x[((size_t)(b * 64 + c)) * Ndim + nbase + li];
            const __bf16 h = (__bf16)v;
            xhi[kc][jj] = h;
            xlo[kc][jj] = (__bf16)(v - (float)h);
        }
    __syncthreads();

    __bf16* trw = tr[wv];
    const float qs = (jc == 0) ? KS : 1.f;

#pragma unroll
    for (int jt = 0; jt < 4; ++jt) {
        const int rw = 16 * jt + li;
        const int rs = li & 7;
        const bf16x8 ah0 = *(const bf16x8*)(whs + rw * 64 + 8 * (g ^ rs));
        const bf16x8 ah1 = *(const bf16x8*)(whs + rw * 64 + 8 * ((4 + g) ^ rs));
        const bf16x8 al0 = *(const bf16x8*)(wls + rw * 64 + 8 * (g ^ rs));
        const bf16x8 al1 = *(const bf16x8*)(wls + rw * 64 + 8 * ((4 + g) ^ rs));
        f32x4 d = (f32x4){0.f, 0.f, 0.f, 0.f};
        d = __builtin_amdgcn_mfma_f32_16x16x32_bf16(ah0, xhi[0], d, 0, 0, 0);
        d = __builtin_amdgcn_mfma_f32_16x16x32_bf16(ah1, xhi[1], d, 0, 0, 0);
        d = __builtin_amdgcn_mfma_f32_16x16x32_bf16(ah0, xlo[0], d, 0, 0, 0);
        d = __builtin_amdgcn_mfma_f32_16x16x32_bf16(ah1, xlo[1], d, 0, 0, 0);
        d = __builtin_amdgcn_mfma_f32_16x16x32_bf16(al0, xhi[0], d, 0, 0, 0);
        d = __builtin_amdgcn_mfma_f32_16x16x32_bf16(al1, xhi[1], d, 0, 0, 0);

        if (jc == 2) {
#pragma unroll
            for (int r = 0; r < 4; ++r) {
                const int cv = jt * 16 + 4 * g + r;
                Vb[((size_t)(b * 64 + cv)) * Ndim + nbase + li] = (__bf16)d[r];
            }
        } else {
            bf16x4 pk;
#pragma unroll
            for (int r = 0; r < 4; ++r) pk[r] = (__bf16)(d[r] * qs);
            const int gran = (2 * jt + (g >> 1)) ^ (li & 7);
            *(bf16x4*)(trw + li * 64 + gran * 8 + 4 * (g & 1)) = pk;
        }
    }

    if (jc != 2) {
        __bf16* dstm = ((jc == 0) ? Qb : Kb) + ((size_t)b * Ndim + nbase) * 64;
#pragma unroll
        for (int p = 0; p < 2; ++p) {
            const int row = p * 8 + (l >> 3);
            const uint4 vr = *(const uint4*)(
                trw + row * 64 + ((l & 7) ^ (l >> 3)) * 8);
            *(uint4*)(dstm + row * 64 + 8 * (l & 7)) = vr;
        }
    }
}

// ---------------------------------------------------------------------------
// Kernel 2: MFMA flash attention, 32x32x16, fixed-shift softmax (r12),
// with ENRICHED LDS swizzles (both-sides) to kill the 4.19M bank conflicts:
//   K granule ^= ((row>>3)&3)<<1 ; V csw = ((c>>1)^(c>>3))&3.
// ---------------------------------------------------------------------------
__global__ __launch_bounds__(512, 4) void attn_kernel(
    const __bf16* __restrict__ Qb, const __bf16* __restrict__ Kb,
    const __bf16* __restrict__ Vb, const float* __restrict__ fgb,
    const float* __restrict__ w_proj, const float* __restrict__ b_proj,
    float* __restrict__ out)
{
    __shared__ __align__(16) __bf16 kt[4][2][TK * 64];   // [grp][buf][R][c]  32 KB
    __shared__ __align__(16) __bf16 vt[4][2][64 * TK];   // [grp][buf][c][k]  32 KB
    __shared__ __align__(16) float  mtf[4][2][TK];       // mask bias (f32)   1 KB

    const int bx   = blockIdx.x;
    const int b    = bx & 7;
    const int qblk = (bx >> 3) & 63;
    const int tid  = threadIdx.x;
    const int wv   = tid >> 6;
    const int grp  = wv >> 1;
    const int wsub = wv & 1;
    const int l    = tid & 63;
    const int q    = l & 31;
    const int hi   = l >> 5;

    // Q B-frags: B[k=8hi+j+16s][col=q]
    const int qrow = qblk * 64 + wsub * 32 + q;
    const __bf16* qbp = Qb + ((size_t)b * Ndim + qrow) * 64;
    bf16x8 qf[4];
#pragma unroll
    for (int s = 0; s < 4; ++s)
        qf[s] = *(const bf16x8*)(qbp + 16 * s + 8 * hi);

    // ---- staging geometry ----
    const int kbase0 = grp * 1024;
    const __bf16* ksrcc[2];
    const __bf16* vsrcc[2];
    int kdst[2], vdst[2];
#pragma unroll
    for (int cc = 0; cc < 2; ++cc) {
        const int R  = wsub * 16 + cc * 8 + (l >> 3);
        const int pi = (R & 19) | ((R & 4) << 1) | ((R & 8) >> 1);  // swap b2<->b3
        // enriched swizzle: granule ^= (R&7) ^ (((R>>3)&3)<<1)
        ksrcc[cc] = Kb + ((size_t)b * Ndim + kbase0 + pi) * 64
                  + 8 * ((l & 7) ^ (R & 7) ^ (((R >> 3) & 3) << 1));
        kdst[cc]  = (wsub * 16 + cc * 8) * 64;
        const int row = wsub * 32 + cc * 16 + (l >> 2);
        // enriched swizzle: granule ^= ((row>>1)^(row>>3)) & 3
        vsrcc[cc] = Vb + ((size_t)(b * 64 + row)) * Ndim + kbase0
                  + 8 * ((l & 3) ^ (((row >> 1) ^ (row >> 3)) & 3));
        vdst[cc]  = (wsub * 32 + cc * 16) * TK;
    }
    const float* fgbp = fgb + b * Ndim + kbase0;

    auto stage = [&](int t, int buf) {
#pragma unroll
        for (int cc = 0; cc < 2; ++cc)
            gload_lds16(ksrcc[cc] + (size_t)t * (TK * 64), &kt[grp][buf][kdst[cc]]);
#pragma unroll
        for (int cc = 0; cc < 2; ++cc)
            gload_lds16(vsrcc[cc] + t * TK, &vt[grp][buf][vdst[cc]]);
        if (wsub == 0 && l < 8)
            gload_lds16(fgbp + t * 32 + l * 4, &mtf[grp][buf][0]);
    };

    f32x16 acc0 = {}, acc1 = {};
    f32x4  psv  = {};

    stage(0, 0);

    for (int it = 0; it < GNT; ++it) {
        const int buf = it & 1;
        __syncthreads();                  // tile resident
        if (it + 1 < GNT) stage(it + 1, buf ^ 1);

        // mask bias -> C-init: z[r] = bias[key (r&7)+8hi+16(r>>3)]
        const float* mrow = &mtf[grp][buf][0];
        const f32x4 ma = *(const f32x4*)(mrow + 8 * hi);
        const f32x4 mb = *(const f32x4*)(mrow + 8 * hi + 4);
        const f32x4 mc = *(const f32x4*)(mrow + 16 + 8 * hi);
        const f32x4 md = *(const f32x4*)(mrow + 20 + 8 * hi);
        f32x16 z;
#pragma unroll
        for (int r = 0; r < 4; ++r) {
            z[r] = ma[r]; z[4 + r] = mb[r]; z[8 + r] = mc[r]; z[12 + r] = md[r];
        }

        // ---- S^T = K Q^T (one 32x32 tile, K-dim 64 = 4 MFMA) ----
        __builtin_amdgcn_s_setprio(1);
#pragma unroll
        for (int s = 0; s < 4; ++s) {
            const bf16x8 kf = *(const bf16x8*)(
                &kt[grp][buf][q * 64
                    + 8 * ((hi + 2 * s) ^ (q & 7) ^ (((q >> 3) & 3) << 1))]);
            z = __builtin_amdgcn_mfma_f32_32x32x16_bf16(kf, qf[s], z, 0, 0, 0);
        }
        __builtin_amdgcn_s_setprio(0);

        // ---- p = exp2(s); per-lane partial row-sums ----
        f32x16 p;
#pragma unroll
        for (int r = 0; r < 16; ++r) {
            p[r] = fexp2(z[r]);
            psv[r & 3] += p[r];
        }
        bf16x8 pb0, pb1;
#pragma unroll
        for (int j = 0; j < 8; ++j) {
            pb0[j] = (__bf16)p[j];
            pb1[j] = (__bf16)p[8 + j];
        }

        // ---- O^T += V^T P^T (2 c-halves x 2 K-pieces) ----
        __builtin_amdgcn_s_setprio(1);
#pragma unroll
        for (int h = 0; h < 2; ++h) {
            const int c   = 32 * h + q;
            const int csw = ((c >> 1) ^ (c >> 3)) & 3;
            const bf16x8 vf0 = *(const bf16x8*)(&vt[grp][buf][c * 32 + 8 * ((hi)     ^ csw)]);
            const bf16x8 vf1 = *(const bf16x8*)(&vt[grp][buf][c * 32 + 8 * ((hi + 2) ^ csw)]);
            if (h == 0) {
                acc0 = __builtin_amdgcn_mfma_f32_32x32x16_bf16(vf0, pb0, acc0, 0, 0, 0);
                acc0 = __builtin_amdgcn_mfma_f32_32x32x16_bf16(vf1, pb1, acc0, 0, 0, 0);
            } else {
                acc1 = __builtin_amdgcn_mfma_f32_32x32x16_bf16(vf0, pb0, acc1, 0, 0, 0);
                acc1 = __builtin_amdgcn_mfma_f32_32x32x16_bf16(vf1, pb1, acc1, 0, 0, 0);
            }
        }
        __builtin_amdgcn_s_setprio(0);
    }

    // ---- row-sum: horizontal + cross-hi (once) ----
    float lsum = (psv[0] + psv[1]) + (psv[2] + psv[3]);
    lsum += __shfl_xor(lsum, 32);

    // ---- 4-way merge via LDS overlay (plain sums, shared fixed shift) ----
    float* mlb = (float*)&kt[0][0][0];
    __syncthreads();

    auto chunk = [&](int cidx) -> float* {
        return (cidx < 4) ? (float*)&vt[0][0][0] + cidx * 2048
                          : mlb + 256 + (cidx - 4) * 2048;
    };

    if (grp > 0) {
        const int pp = grp - 1;
        if (l < 32) mlb[(pp * 2 + wsub) * 32 + l] = lsum;
        float* o = chunk(pp * 2 + wsub);
#pragma unroll
        for (int fi = 0; fi < 8; ++fi) {
            f32x4 v;
#pragma unroll
            for (int e = 0; e < 4; ++e)
                v[e] = (fi < 4) ? acc0[(fi & 3) * 4 + e] : acc1[(fi & 3) * 4 + e];
            *(f32x4*)(o + (fi * 64 + l) * 4) = v;
        }
    }
    __syncthreads();
    if (grp > 0) return;

    float Lt = lsum;
#pragma unroll
    for (int pp = 0; pp < 3; ++pp)
        Lt += mlb[(pp * 2 + wsub) * 32 + q];
    const float inv = 1.f / Lt;

    f32x16 m0 = acc0, m1 = acc1;
#pragma unroll
    for (int pp = 0; pp < 3; ++pp) {
        const float* o = chunk(pp * 2 + wsub);
#pragma unroll
        for (int fi = 0; fi < 8; ++fi) {
            const f32x4 v = *(const f32x4*)(o + (fi * 64 + l) * 4);
#pragma unroll
            for (int e = 0; e < 4; ++e) {
                if (fi < 4) m0[(fi & 3) * 4 + e] += v[e];
                else        m1[(fi & 3) * 4 + e] += v[e];
            }
        }
    }

    // ---- normalized O -> B-frags (sigma-permuted k order, lane-local) ----
    bf16x8 ob[4];
#pragma unroll
    for (int s = 0; s < 4; ++s)
#pragma unroll
        for (int j = 0; j < 8; ++j) {
            const float vv = (s < 2) ? m0[j + 8 * (s & 1)] : m1[j + 8 * (s & 1)];
            ob[s][j] = (__bf16)(vv * inv);
        }

    // ---- fused out-projection: W columns sigma-permuted to match ----
    const int nb = qblk * 64 + wsub * 32;
#pragma unroll
    for (int H = 0; H < 2; ++H) {
        const int co = 32 * H + q;
        f32x16 y = {};
#pragma unroll
        for (int s = 0; s < 4; ++s) {
            const float* wr = w_proj + co * 64 + 4 * hi + 16 * s;
            const float4 fA = *(const float4*)(wr);
            const float4 fB = *(const float4*)(wr + 8);
            bf16x8 wf;
            wf[0] = (__bf16)fA.x; wf[1] = (__bf16)fA.y;
            wf[2] = (__bf16)fA.z; wf[3] = (__bf16)fA.w;
            wf[4] = (__bf16)fB.x; wf[5] = (__bf16)fB.y;
            wf[6] = (__bf16)fB.z; wf[7] = (__bf16)fB.w;
            y = __builtin_amdgcn_mfma_f32_32x32x16_bf16(wf, ob[s], y, 0, 0, 0);
        }
#pragma unroll
        for (int rq = 0; rq < 4; ++rq) {
            const f32x4 bp = *(const f32x4*)(b_proj + 32 * H + 4 * hi + 8 * rq);
#pragma unroll
            for (int e = 0; e < 4; ++e) {
                const int co2 = 32 * H + e + 8 * rq + 4 * hi;
                out[((size_t)(b * 64 + co2)) * Ndim + nb + q] = y[rq * 4 + e] + bp[e];
            }
        }
    }
}

extern "C" void kernel_launch(void* const* d_in, const int* in_sizes, int n_in,
                              void* d_out, int out_size, void* d_ws, size_t ws_size,
                              hipStream_t stream) {
    const float* x      = (const float*)d_in[0];
    const int*   fg     = (const int*)d_in[1];
    const float* w_qkv  = (const float*)d_in[2];
    const float* w_proj = (const float*)d_in[3];
    const float* b_proj = (const float*)d_in[4];
    float* out = (float*)d_out;

    const size_t per = (size_t)Bdim * Cdim * Ndim;   // 2,097,152 elems
    __bf16* Qb  = (__bf16*)d_ws;
    __bf16* Kb  = Qb + per;
    __bf16* Vb  = Kb + per;
    float*  fgb = (float*)(Vb + per);                // 128 KB

    qkv_mfma_kernel<<<dim3(Bdim * (Ndim / 64) * 3), dim3(256), 0, stream>>>(
        x, w_qkv, fg, Qb, Kb, Vb, fgb);
    attn_kernel<<<dim3(Bdim * (Ndim / 64)), dim3(512), 0, stream>>>(
        Qb, Kb, Vb, fgb, w_proj, b_proj, out);
}